// Round 7
// baseline (495.632 us; speedup 1.0000x reference)
//
#include <hip/hip_runtime.h>
#include <hip/hip_bf16.h>

using u16 = unsigned short;
using u32 = unsigned int;
typedef short short8 __attribute__((ext_vector_type(8)));
typedef float f32x4 __attribute__((ext_vector_type(4)));

#define B_  2
#define S_  2048
#define E_  768
#define BS_ 4096

#define L2E_ 1.44269504088896f
#define FML2_ 17.3123404906676f   // 12.0 * log2(e) fixed softmax stabilizer

__device__ __forceinline__ u16 f2bf(float f) {
  __hip_bfloat16 h = __float2bfloat16(f);
  return *reinterpret_cast<u16*>(&h);
}

__device__ __forceinline__ float bf2f(u16 b) {
  u32 bits = (u32)b << 16;
  return *reinterpret_cast<float*>(&bits);
}

__device__ __forceinline__ u32 pk2(float a, float b) {
  return (u32)f2bf(a) | ((u32)f2bf(b) << 16);
}

// async global->LDS, 16B per lane. LDS dest must be wave-uniform base + lane*16.
__device__ __forceinline__ void gld16(const void* g, void* l) {
  __builtin_amdgcn_global_load_lds(
      (const __attribute__((address_space(1))) u32*)g,
      (__attribute__((address_space(3))) u32*)l, 16, 0, 0);
}

// ---------------- conversion / misc kernels ----------------

__global__ __launch_bounds__(256) void conv_x_k(const float* __restrict__ x,
                                                u16* __restrict__ xb, int n4) {
  int i = blockIdx.x * 256 + threadIdx.x;
  if (i >= n4) return;
  float4 v = reinterpret_cast<const float4*>(x)[i];
  reinterpret_cast<uint2*>(xb)[i] = make_uint2(pk2(v.x, v.y), pk2(v.z, v.w));
}

// plain bf16 convert of ro_w and co_w (no transpose): roB/coB[in][out]
__global__ __launch_bounds__(256) void conv_w_k(const float* __restrict__ ro,
                                                const float* __restrict__ co,
                                                u16* __restrict__ roB,
                                                u16* __restrict__ coB) {
  const int n4 = 768 * 768 / 4;
  int i = blockIdx.x * 256 + threadIdx.x;
  const float* src = (i < n4) ? ro : co;
  u16* dst = (i < n4) ? roB : coB;
  int k = (i < n4) ? i : i - n4;
  if (k >= n4) return;
  float4 v = reinterpret_cast<const float4*>(src)[k];
  reinterpret_cast<uint2*>(dst)[k] = make_uint2(pk2(v.x, v.y), pk2(v.z, v.w));
}

__global__ __launch_bounds__(256) void bias_k(
    const float* rqb, const float* rkb, const float* rvb,
    const float* cqb, const float* ckb, const float* cvb,
    const float* rob, const float* cob,
    const float* rcb, const float* ccb,
    float* bqkv, float* bproj, float* zb) {
  int t = blockIdx.x * 256 + threadIdx.x;
  if (t < 4608) {
    int seg = t / 768, i = t - seg * 768;
    float v = 0.f;
    if      (seg == 0) v = rqb[i] + rcb[i];   // cultural bias folds into Q bias
    else if (seg == 1) v = rkb[i];
    else if (seg == 2) v = rvb[i];
    else if (seg == 3) v = cqb[i] + ccb[i];
    else if (seg == 4) v = ckb[i];
    else               v = cvb[i];
    bqkv[t] = v;
  } else if (t < 6144) {
    int u = t - 4608;
    bproj[u] = (u < 768) ? rob[u] : cob[u - 768];
  } else if (t < 6912) {
    zb[t - 6144] = 0.f;
  }
}

// folded final bias: bfin[o] = sum_i bproj[i]*out_w[i][o] + out_b[o]
// one wave per o; outwT[o][i] contiguous reads.
__global__ __launch_bounds__(64) void bfin_k(
    const float* __restrict__ bproj, const u16* __restrict__ outwT,
    const float* __restrict__ outb, float* __restrict__ bfin) {
  int o = blockIdx.x;
  int lane = threadIdx.x;
  const u16* row = outwT + (size_t)o * 1536;
  float s = 0.f;
  for (int i = lane; i < 1536; i += 64) s += bproj[i] * bf2f(row[i]);
  s += __shfl_xor(s, 1);
  s += __shfl_xor(s, 2);
  s += __shfl_xor(s, 4);
  s += __shfl_xor(s, 8);
  s += __shfl_xor(s, 16);
  s += __shfl_xor(s, 32);
  if (lane == 0) bfin[o] = s + outb[o];
}

struct TP {
  const float* src[9];
  u16* dst[9];
  int rows[9];
};

// dst[c][r] = bf16(src[r][c]); src is [rows][768]
__global__ __launch_bounds__(256) void transpose_k(TP p) {
  int mi = blockIdx.z;
  int rows = p.rows[mi];
  int r0 = blockIdx.y * 32;
  if (r0 >= rows) return;
  int c0 = blockIdx.x * 32;
  const float* src = p.src[mi];
  u16* dst = p.dst[mi];
  __shared__ float t[32][33];
  int tx = threadIdx.x & 31, ty = threadIdx.x >> 5;
#pragma unroll
  for (int d = 0; d < 4; ++d) {
    int r = ty + d * 8;
    t[r][tx] = src[(size_t)(r0 + r) * 768 + c0 + tx];
  }
  __syncthreads();
#pragma unroll
  for (int d = 0; d < 4; ++d) {
    int c = ty + d * 8;
    dst[(size_t)(c0 + c) * rows + r0 + tx] = f2bf(t[tx][c]);
  }
}

// ============ transposed GEMM: computes C^T with A[M][K], BT[N][K]; lane's 4
// acc values are CONSECUTIVE M-rows -> packed 8B stores.
// MODE 0: bf16 -> Cout[col*ldc+row], MODE 1: fp32 float4, MODE 2: QKVT ====

template<int MODE>
__global__ __launch_bounds__(256) void gemm_t_k(
    const u16* __restrict__ A, int lda,
    const u16* __restrict__ BT, int ldb,
    const float* __restrict__ bias, int K,
    const u16* __restrict__ A2, int msplit, int bofs,
    void* __restrict__ Cout, int ldc,
    u16* __restrict__ Qr, u16* __restrict__ Kr, u16* __restrict__ Vtr,
    u16* __restrict__ Qc, u16* __restrict__ Kc, u16* __restrict__ Vtc) {
  __shared__ u16 lA[128 * 32];
  __shared__ u16 lB[128 * 32];
  const int tid = threadIdx.x, w = tid >> 6, lane = tid & 63;
  const int quad = lane >> 4, l15 = lane & 15;
  const int m0 = blockIdx.y * 128, n0 = blockIdx.x * 128;
  if (msplit && m0 >= msplit) { A = A2 - (size_t)msplit * lda; BT += bofs; }

  const f32x4 z4 = {0.f, 0.f, 0.f, 0.f};
  f32x4 acc[4][4];
#pragma unroll
  for (int i = 0; i < 4; ++i)
#pragma unroll
    for (int j = 0; j < 4; ++j) acc[i][j] = z4;

  const int sr = w * 32 + (lane >> 2);
  const int scp = lane & 3;

  for (int kt = 0; kt < K; kt += 32) {
    int r1 = sr, r2 = sr + 16;
    int c1 = (scp - (r1 >> 2)) & 3;
    int c2 = (scp - (r2 >> 2)) & 3;
    gld16(A + (size_t)(m0 + r1) * lda + kt + c1 * 8, &lA[r1 * 32 + scp * 8]);
    gld16(A + (size_t)(m0 + r2) * lda + kt + c2 * 8, &lA[r2 * 32 + scp * 8]);
    gld16(BT + (size_t)(n0 + r1) * ldb + kt + c1 * 8, &lB[r1 * 32 + scp * 8]);
    gld16(BT + (size_t)(n0 + r2) * ldb + kt + c2 * 8, &lB[r2 * 32 + scp * 8]);
    __syncthreads();
    short8 af[4], bg[4];
#pragma unroll
    for (int i = 0; i < 4; ++i) {
      int r = (w >> 1) * 64 + i * 16 + l15;
      af[i] = *reinterpret_cast<const short8*>(&lA[r * 32 + ((quad + (r >> 2)) & 3) * 8]);
    }
#pragma unroll
    for (int j = 0; j < 4; ++j) {
      int r = (w & 1) * 64 + j * 16 + l15;
      bg[j] = *reinterpret_cast<const short8*>(&lB[r * 32 + ((quad + (r >> 2)) & 3) * 8]);
    }
#pragma unroll
    for (int i = 0; i < 4; ++i)
#pragma unroll
      for (int j = 0; j < 4; ++j)
        acc[i][j] = __builtin_amdgcn_mfma_f32_16x16x32_bf16(af[i], bg[j], acc[i][j], 0, 0, 0);
    __syncthreads();
  }

  const int seg = (MODE == 2) ? (m0 / 768) : 0;
#pragma unroll
  for (int i = 0; i < 4; ++i) {
    int f = m0 + (w >> 1) * 64 + i * 16 + quad * 4;   // M-row base (4 consecutive)
    float4 b4 = *reinterpret_cast<const float4*>(bias + f);
#pragma unroll
    for (int j = 0; j < 4; ++j) {
      int t = n0 + (w & 1) * 64 + j * 16 + l15;        // N-col
      float v0 = acc[i][j][0] + b4.x;
      float v1 = acc[i][j][1] + b4.y;
      float v2 = acc[i][j][2] + b4.z;
      float v3 = acc[i][j][3] + b4.w;
      if (MODE == 0) {
        *reinterpret_cast<uint2*>((u16*)Cout + (size_t)t * ldc + f) =
            make_uint2(pk2(v0, v1), pk2(v2, v3));
      } else if (MODE == 1) {
        *reinterpret_cast<float4*>((float*)Cout + (size_t)t * ldc + f) =
            make_float4(v0, v1, v2, v3);
      } else {
        int b = t >> 11, s = t & 2047;
        int fs = f - seg * 768;
        if (seg == 0) {
          int h = fs >> 7, d = fs & 127;
          *reinterpret_cast<uint2*>(Qr + ((size_t)(b * 6 + h) * 2048 + s) * 128 + d) =
              make_uint2(pk2(v0, v1), pk2(v2, v3));
        } else if (seg == 1) {
          int h = fs >> 7, d = fs & 127;
          *reinterpret_cast<uint2*>(Kr + ((size_t)(b * 6 + h) * 2048 + s) * 128 + d) =
              make_uint2(pk2(v0, v1), pk2(v2, v3));
        } else if (seg == 2) {
          int h = fs >> 7, d = fs & 127;
          u16* vp = Vtr + ((size_t)(b * 6 + h) * 128 + d) * 2048 + s;
          vp[0] = f2bf(v0); vp[2048] = f2bf(v1); vp[4096] = f2bf(v2); vp[6144] = f2bf(v3);
        } else if (seg == 3) {
          int h = fs / 384, d = fs - h * 384;
          *reinterpret_cast<uint2*>(Qc + ((size_t)(b * 2 + h) * 2048 + s) * 384 + d) =
              make_uint2(pk2(v0, v1), pk2(v2, v3));
        } else if (seg == 4) {
          int h = fs / 384, d = fs - h * 384;
          *reinterpret_cast<uint2*>(Kc + ((size_t)(b * 2 + h) * 2048 + s) * 384 + d) =
              make_uint2(pk2(v0, v1), pk2(v2, v3));
        } else {
          int h = fs / 384, d = fs - h * 384;
          u16* vp = Vtc + ((size_t)(b * 2 + h) * 384 + d) * 2048 + s;
          vp[0] = f2bf(v0); vp[2048] = f2bf(v1); vp[4096] = f2bf(v2); vp[6144] = f2bf(v3);
        }
      }
    }
  }
}

// ---------------- fused regular-branch attention, direct-load version -------
// One block per (head, 64-query stripe). Q/K/V fragments loaded straight from
// global to VGPRs (16B/lane, 64B segments, L2-resident); only P round-trips
// through LDS. 2 barriers per 128-key tile, 64 MFMA between barriers.
__global__ __launch_bounds__(256) void attn_freg_k(
    const u16* __restrict__ Qr, const u16* __restrict__ Kr,
    const u16* __restrict__ Vtr, const float* __restrict__ am,
    u16* __restrict__ AO, float scl) {
  __shared__ u16 lP[64 * 128];    // 16 KB
  __shared__ float lL[2][64];

  const int tid = threadIdx.x, w = tid >> 6, lane = tid & 63;
  const int quad = lane >> 4, l15 = lane & 15;
  // XCD swizzle: group each head's stripes for K/V L2 reuse
  const int L = blockIdx.x;
  const int gg = (L & 7) * 48 + (L >> 3);   // [0,384)
  const int bh = gg >> 5;                    // head [0,12)
  const int q0 = (gg & 31) * 64;             // query stripe
  const int b = bh / 6, h = bh - b * 6;
  const int khalf = w >> 1, qhalf = w & 1;

  const u16* Qb = Qr + ((size_t)bh * S_ + q0) * 128;
  const u16* Kb0 = Kr + (size_t)bh * S_ * 128;
  const u16* Vb0 = Vtr + (size_t)bh * 128 * S_;
  const float* amb = am + b * S_;

  // Q fragments (B-operand): n=q=l15, k=kdim quad*8 within 32-chunk c
  short8 qf[2][4];
#pragma unroll
  for (int j = 0; j < 2; ++j)
#pragma unroll
    for (int c = 0; c < 4; ++c)
      qf[j][c] = *reinterpret_cast<const short8*>(
          Qb + (size_t)(qhalf * 32 + j * 16 + l15) * 128 + c * 32 + quad * 8);

  const f32x4 z4 = {0.f, 0.f, 0.f, 0.f};
  f32x4 accO[4][2];
#pragma unroll
  for (int i = 0; i < 4; ++i)
#pragma unroll
    for (int j = 0; j < 2; ++j) accO[i][j] = z4;
  float lsum[2] = {0.f, 0.f};

  for (int t = 0; t < 16; ++t) {
    // ---- S = K·Q^T : direct K fragment loads, no barriers ----
    f32x4 accS[4][2];
#pragma unroll
    for (int i = 0; i < 4; ++i)
#pragma unroll
      for (int j = 0; j < 2; ++j) accS[i][j] = z4;
    const u16* Kt = Kb0 + (size_t)t * 128 * 128;
#pragma unroll
    for (int c = 0; c < 4; ++c) {
      short8 kf[4];
#pragma unroll
      for (int i = 0; i < 4; ++i)
        kf[i] = *reinterpret_cast<const short8*>(
            Kt + (size_t)(khalf * 64 + i * 16 + l15) * 128 + c * 32 + quad * 8);
#pragma unroll
      for (int i = 0; i < 4; ++i)
#pragma unroll
        for (int j = 0; j < 2; ++j)
          accS[i][j] = __builtin_amdgcn_mfma_f32_16x16x32_bf16(kf[i], qf[j][c], accS[i][j], 0, 0, 0);
    }

    __syncthreads();   // all waves done reading lP from previous tile

    // ---- exp + P -> LDS (xor-16 swizzle) ----
#pragma unroll
    for (int i = 0; i < 4; ++i) {
      int kb = khalf * 64 + i * 16 + quad * 4;
      float4 a4 = *reinterpret_cast<const float4*>(amb + t * 128 + kb);
      float p0c = fmaf(a4.x, L2E_, -FML2_);
      float p1c = fmaf(a4.y, L2E_, -FML2_);
      float p2c = fmaf(a4.z, L2E_, -FML2_);
      float p3c = fmaf(a4.w, L2E_, -FML2_);
#pragma unroll
      for (int j = 0; j < 2; ++j) {
        int q = qhalf * 32 + j * 16 + l15;
        float p0 = exp2f(fmaf(accS[i][j][0], scl, p0c));
        float p1 = exp2f(fmaf(accS[i][j][1], scl, p1c));
        float p2 = exp2f(fmaf(accS[i][j][2], scl, p2c));
        float p3 = exp2f(fmaf(accS[i][j][3], scl, p3c));
        lsum[j] += (p0 + p1) + (p2 + p3);
        int s = ((kb >> 3) ^ (q & 15));
        *reinterpret_cast<uint2*>(&lP[q * 128 + s * 8 + (kb & 7)]) =
            make_uint2(pk2(p0, p1), pk2(p2, p3));
      }
    }
    __syncthreads();   // lP visible

    // ---- O += V·P^T : direct V fragment loads ----
#pragma unroll
    for (int c = 0; c < 4; ++c) {
      short8 vf[4];
#pragma unroll
      for (int i = 0; i < 4; ++i)
        vf[i] = *reinterpret_cast<const short8*>(
            Vb0 + (size_t)(khalf * 64 + i * 16 + l15) * S_ + t * 128 + c * 32 + quad * 8);
      short8 bg[2];
#pragma unroll
      for (int j = 0; j < 2; ++j) {
        int q = qhalf * 32 + j * 16 + l15;
        int s = (4 * c + quad) ^ (q & 15);
        bg[j] = *reinterpret_cast<const short8*>(&lP[q * 128 + s * 8]);
      }
#pragma unroll
      for (int i = 0; i < 4; ++i)
#pragma unroll
        for (int j = 0; j < 2; ++j)
          accO[i][j] = __builtin_amdgcn_mfma_f32_16x16x32_bf16(vf[i], bg[j], accO[i][j], 0, 0, 0);
    }
  }

  // ---- l reduction across quads and k-half waves ----
#pragma unroll
  for (int j = 0; j < 2; ++j) {
    float s = lsum[j];
    s += __shfl_xor(s, 16);
    s += __shfl_xor(s, 32);
    if (lane < 16) lL[khalf][qhalf * 32 + j * 16 + lane] = s;
  }
  __syncthreads();

  float invl[2];
#pragma unroll
  for (int j = 0; j < 2; ++j) {
    int q = qhalf * 32 + j * 16 + l15;
    invl[j] = 1.f / (lL[0][q] + lL[1][q]);
  }
#pragma unroll
  for (int i = 0; i < 4; ++i) {
    int d = khalf * 64 + i * 16 + quad * 4;
#pragma unroll
    for (int j = 0; j < 2; ++j) {
      int tok = q0 + qhalf * 32 + j * 16 + l15;
      float v0 = accO[i][j][0] * invl[j];
      float v1 = accO[i][j][1] * invl[j];
      float v2 = accO[i][j][2] * invl[j];
      float v3 = accO[i][j][3] * invl[j];
      *reinterpret_cast<uint2*>(AO + ((size_t)(b * S_ + tok)) * 1536 + h * 128 + d) =
          make_uint2(pk2(v0, v1), pk2(v2, v3));
    }
  }
}

// ---------------- cultural g1 (transposed): S^T[k][q] = K·Q^T ----------------
__global__ __launch_bounds__(256) void attn_g1_k(
    const u16* __restrict__ Qc, const u16* __restrict__ Kc,
    u16* __restrict__ Pc, float* __restrict__ Lp,
    const float* __restrict__ am, const float* __restrict__ cmask,
    float sCul) {
  __shared__ u16 lA[128 * 32];
  __shared__ u16 lB[128 * 32];
  const int tid = threadIdx.x, w = tid >> 6, lane = tid & 63;
  const int quad = lane >> 4, l15 = lane & 15;
  const int m0 = blockIdx.y * 128, n0 = blockIdx.x * 128;  // m=key, n=query
  const int hc = blockIdx.z;
  const int K = 384;
  const u16* A = Kc + (size_t)hc * S_ * 384;
  const u16* BT = Qc + (size_t)hc * S_ * 384;
  u16* P = Pc + (size_t)hc * (size_t)S_ * S_;
  const int b = hc >> 1;
  const float* cm = cmask + (size_t)b * S_ * S_;
  const float scl = sCul;

  const f32x4 z4 = {0.f, 0.f, 0.f, 0.f};
  f32x4 acc[4][4];
#pragma unroll
  for (int i = 0; i < 4; ++i)
#pragma unroll
    for (int j = 0; j < 4; ++j) acc[i][j] = z4;

  const int sr = w * 32 + (lane >> 2);
  const int scp = lane & 3;

  for (int kt = 0; kt < K; kt += 32) {
    int r1 = sr, r2 = sr + 16;
    int c1 = (scp - (r1 >> 2)) & 3;
    int c2 = (scp - (r2 >> 2)) & 3;
    gld16(A + (size_t)(m0 + r1) * K + kt + c1 * 8, &lA[r1 * 32 + scp * 8]);
    gld16(A + (size_t)(m0 + r2) * K + kt + c2 * 8, &lA[r2 * 32 + scp * 8]);
    gld16(BT + (size_t)(n0 + r1) * K + kt + c1 * 8, &lB[r1 * 32 + scp * 8]);
    gld16(BT + (size_t)(n0 + r2) * K + kt + c2 * 8, &lB[r2 * 32 + scp * 8]);
    __syncthreads();
    short8 af[4], bg[4];
#pragma unroll
    for (int i = 0; i < 4; ++i) {
      int r = (w >> 1) * 64 + i * 16 + l15;
      af[i] = *reinterpret_cast<const short8*>(&lA[r * 32 + ((quad + (r >> 2)) & 3) * 8]);
    }
#pragma unroll
    for (int j = 0; j < 4; ++j) {
      int r = (w & 1) * 64 + j * 16 + l15;
      bg[j] = *reinterpret_cast<const short8*>(&lB[r * 32 + ((quad + (r >> 2)) & 3) * 8]);
    }
#pragma unroll
    for (int i = 0; i < 4; ++i)
#pragma unroll
      for (int j = 0; j < 4; ++j)
        acc[i][j] = __builtin_amdgcn_mfma_f32_16x16x32_bf16(af[i], bg[j], acc[i][j], 0, 0, 0);
    __syncthreads();
  }

  const float* amb = am + b * S_;
  float lsum[4] = {0.f, 0.f, 0.f, 0.f};
#pragma unroll
  for (int i = 0; i < 4; ++i) {
    int kb = m0 + (w >> 1) * 64 + i * 16 + quad * 4;    // 4 consecutive keys
    float4 a4 = *reinterpret_cast<const float4*>(amb + kb);
    float pre0 = fmaf(a4.x, L2E_, -FML2_);
    float pre1 = fmaf(a4.y, L2E_, -FML2_);
    float pre2 = fmaf(a4.z, L2E_, -FML2_);
    float pre3 = fmaf(a4.w, L2E_, -FML2_);
#pragma unroll
    for (int j = 0; j < 4; ++j) {
      int q = n0 + (w & 1) * 64 + j * 16 + l15;
      float4 cmv = *reinterpret_cast<const float4*>(cm + (size_t)q * S_ + kb);
      float c0 = fmaf(cmv.x, L2E_, pre0);
      float c1 = fmaf(cmv.y, L2E_, pre1);
      float c2 = fmaf(cmv.z, L2E_, pre2);
      float c3 = fmaf(cmv.w, L2E_, pre3);
      float p0 = exp2f(fmaf(acc[i][j][0], scl, c0));
      float p1 = exp2f(fmaf(acc[i][j][1], scl, c1));
      float p2 = exp2f(fmaf(acc[i][j][2], scl, c2));
      float p3 = exp2f(fmaf(acc[i][j][3], scl, c3));
      lsum[j] += (p0 + p1) + (p2 + p3);
      *reinterpret_cast<uint2*>(P + (size_t)q * S_ + kb) =
          make_uint2(pk2(p0, p1), pk2(p2, p3));
    }
  }
#pragma unroll
  for (int j = 0; j < 4; ++j) {
    float s = lsum[j];
    s += __shfl_xor(s, 16);
    s += __shfl_xor(s, 32);
    if (lane < 16)
      Lp[(size_t)hc * (32 * S_) + ((size_t)((m0 >> 7) * 2 + (w >> 1))) * S_ +
         n0 + (w & 1) * 64 + j * 16 + lane] = s;
  }
}

// ---------------- cultural g2 (transposed): O^T[d][q] = Vt·P^T ----------------
__global__ __launch_bounds__(256) void attn_g2_k(
    const u16* __restrict__ Pc, const u16* __restrict__ Vtc,
    const float* __restrict__ Lp, u16* __restrict__ AO) {
  const int hc = blockIdx.z;
  const int m0 = blockIdx.y * 128, n0 = blockIdx.x * 128;  // m=feat, n=query
  const u16* A = Vtc + (size_t)hc * 384 * S_;
  const u16* BT = Pc + (size_t)hc * (size_t)S_ * S_;
  const int b = hc >> 1;
  const int colbase = 768 + (hc & 1) * 384;
  __shared__ u16 lA[128 * 32];
  __shared__ u16 lB[128 * 32];
  __shared__ float lL[128];
  const int tid = threadIdx.x, w = tid >> 6, lane = tid & 63;
  const int quad = lane >> 4, l15 = lane & 15;

  if (tid < 128) {
    const float* lp = Lp + (size_t)hc * (32 * S_) + (n0 + tid);
    float s = 0.f;
#pragma unroll
    for (int g = 0; g < 32; ++g) s += lp[(size_t)g * S_];
    lL[tid] = 1.f / s;
  }

  const f32x4 z4 = {0.f, 0.f, 0.f, 0.f};
  f32x4 acc[4][4];
#pragma unroll
  for (int i = 0; i < 4; ++i)
#pragma unroll
    for (int j = 0; j < 4; ++j) acc[i][j] = z4;

  const int sr = w * 32 + (lane >> 2);
  const int scp = lane & 3;

  for (int kt = 0; kt < S_; kt += 32) {
    int r1 = sr, r2 = sr + 16;
    int c1 = (scp - (r1 >> 2)) & 3;
    int c2 = (scp - (r2 >> 2)) & 3;
    gld16(A + (size_t)(m0 + r1) * S_ + kt + c1 * 8, &lA[r1 * 32 + scp * 8]);
    gld16(A + (size_t)(m0 + r2) * S_ + kt + c2 * 8, &lA[r2 * 32 + scp * 8]);
    gld16(BT + (size_t)(n0 + r1) * S_ + kt + c1 * 8, &lB[r1 * 32 + scp * 8]);
    gld16(BT + (size_t)(n0 + r2) * S_ + kt + c2 * 8, &lB[r2 * 32 + scp * 8]);
    __syncthreads();
    short8 af[4], bg[4];
#pragma unroll
    for (int i = 0; i < 4; ++i) {
      int r = (w >> 1) * 64 + i * 16 + l15;
      af[i] = *reinterpret_cast<const short8*>(&lA[r * 32 + ((quad + (r >> 2)) & 3) * 8]);
    }
#pragma unroll
    for (int j = 0; j < 4; ++j) {
      int r = (w & 1) * 64 + j * 16 + l15;
      bg[j] = *reinterpret_cast<const short8*>(&lB[r * 32 + ((quad + (r >> 2)) & 3) * 8]);
    }
#pragma unroll
    for (int i = 0; i < 4; ++i)
#pragma unroll
      for (int j = 0; j < 4; ++j)
        acc[i][j] = __builtin_amdgcn_mfma_f32_16x16x32_bf16(af[i], bg[j], acc[i][j], 0, 0, 0);
    __syncthreads();
  }

  float invl[4];
#pragma unroll
  for (int j = 0; j < 4; ++j) invl[j] = lL[(w & 1) * 64 + j * 16 + l15];
#pragma unroll
  for (int i = 0; i < 4; ++i) {
    int feat = colbase + m0 + (w >> 1) * 64 + i * 16 + quad * 4;
#pragma unroll
    for (int j = 0; j < 4; ++j) {
      int q = n0 + (w & 1) * 64 + j * 16 + l15;
      float v0 = acc[i][j][0] * invl[j];
      float v1 = acc[i][j][1] * invl[j];
      float v2 = acc[i][j][2] * invl[j];
      float v3 = acc[i][j][3] * invl[j];
      *reinterpret_cast<uint2*>(AO + ((size_t)(b * S_ + q)) * 1536 + feat) =
          make_uint2(pk2(v0, v1), pk2(v2, v3));
    }
  }
}

// ---------------- launcher ----------------

extern "C" void kernel_launch(void* const* d_in, const int* in_sizes, int n_in,
                              void* d_out, int out_size, void* d_ws, size_t ws_size,
                              hipStream_t stream) {
  const float* x     = (const float*)d_in[0];
  const float* cmask = (const float*)d_in[1];
  const float* amask = (const float*)d_in[2];
  const float* W[8]  = { (const float*)d_in[3], (const float*)d_in[4], (const float*)d_in[5],
                         (const float*)d_in[6], (const float*)d_in[7], (const float*)d_in[8],
                         (const float*)d_in[9], (const float*)d_in[10] };
  const float* rq_b = (const float*)d_in[11];
  const float* rk_b = (const float*)d_in[12];
  const float* rv_b = (const float*)d_in[13];
  const float* ro_b = (const float*)d_in[14];
  const float* cq_b = (const float*)d_in[15];
  const float* ck_b = (const float*)d_in[16];
  const float* cv_b = (const float*)d_in[17];
  const float* co_b = (const float*)d_in[18];
  const float* r_cb = (const float*)d_in[19];
  const float* c_cb = (const float*)d_in[20];
  const float* out_w = (const float*)d_in[21];
  const float* out_b = (const float*)d_in[22];

  char* p = (char*)d_ws;
  auto carve = [&](size_t bytes) -> void* {
    void* r = (void*)p;
    p += (bytes + 255) & ~(size_t)255;
    return r;
  };
  u16* Xb    = (u16*)carve((size_t)BS_ * E_ * 2);       // dead after QKV gemm
  u16* WqkvT = (u16*)carve((size_t)4608 * 768 * 2);     // dead after QKV gemm
  u16* roB   = (u16*)carve((size_t)768 * 768 * 2);      // ro_w bf16 [in][out]
  u16* coB   = (u16*)carve((size_t)768 * 768 * 2);      // co_w bf16 [in][out]
  u16* outwT = (u16*)carve((size_t)768 * 1536 * 2);
  u16* WfT   = (u16*)carve((size_t)768 * 1536 * 2);     // combined final weight^T
  float* bqkv  = (float*)carve(4608 * 4);
  float* bproj = (float*)carve(1536 * 4);
  float* zb    = (float*)carve(768 * 4);
  float* bfin  = (float*)carve(768 * 4);
  u16* Qr  = (u16*)carve((size_t)B_ * 6 * S_ * 128 * 2);
  u16* Kr  = (u16*)carve((size_t)B_ * 6 * S_ * 128 * 2);
  u16* Vtr = (u16*)carve((size_t)B_ * 6 * S_ * 128 * 2);
  u16* Qc  = (u16*)carve((size_t)B_ * 2 * S_ * 384 * 2);
  u16* Kc  = (u16*)carve((size_t)B_ * 2 * S_ * 384 * 2);
  u16* Vtc = (u16*)carve((size_t)B_ * 2 * S_ * 384 * 2);
  u16* AO  = (u16*)carve((size_t)BS_ * 1536 * 2);
  u16* Pcul = (u16*)carve((size_t)4 * S_ * S_ * 2);     // 33.6 MB
  // Lp aliases dead Xb region (1 MB <= 6.3 MB)
  float* Lp = (float*)Xb;

  const float sReg = 0.08838834764831845f * L2E_;
  const float sCul = 0.05103103630798288f * L2E_;

  conv_x_k<<<dim3(BS_ * E_ / 4 / 256), 256, 0, stream>>>(x, Xb, BS_ * E_ / 4);
  conv_w_k<<<dim3(2 * 768 * 768 / 4 / 256), 256, 0, stream>>>(W[3], W[7], roB, coB);
  bias_k<<<dim3(27), 256, 0, stream>>>(rq_b, rk_b, rv_b, cq_b, ck_b, cv_b,
                                       ro_b, co_b, r_cb, c_cb, bqkv, bproj, zb);

  TP tp;
  const int wsel[6] = {0, 1, 2, 4, 5, 6};  // rq rk rv cq ck cv
  for (int i = 0; i < 6; ++i) {
    tp.src[i] = W[wsel[i]];
    tp.dst[i] = WqkvT + (size_t)i * 768 * 768;
    tp.rows[i] = 768;
  }
  tp.src[6] = out_w; tp.dst[6] = outwT; tp.rows[6] = 1536;  // out_w -> outwT[o][i]
  tp.src[7] = out_w; tp.dst[7] = outwT; tp.rows[7] = 1536;  // (dup, overwritten)
  tp.src[8] = out_w; tp.dst[8] = outwT; tp.rows[8] = 1536;
  transpose_k<<<dim3(24, 48, 7), 256, 0, stream>>>(tp);

  // fused QKV projection, transposed: M=4608 features, N=4096 tokens
  gemm_t_k<2><<<dim3(32, 36), 256, 0, stream>>>(
      WqkvT, 768, Xb, 768, bqkv, 768,
      (const u16*)nullptr, 0, 0, (void*)nullptr, 0,
      Qr, Kr, Vtr, Qc, Kc, Vtc);

  // regular branch: fused attention, direct fragment loads
  attn_freg_k<<<dim3(384), 256, 0, stream>>>(Qr, Kr, Vtr, amask, AO, sReg);

  // cultural branch: two-GEMM path
  attn_g1_k<<<dim3(16, 16, 4), 256, 0, stream>>>(
      Qc, Kc, Pcul, Lp, amask, cmask, sCul);
  attn_g2_k<<<dim3(16, 3, 4), 256, 0, stream>>>(Pcul, Vtc, Lp, AO);

  // weight combine: WfT[o][i] = sum_m ro_w[i][m]*out_w[m][o]  (i<768)
  //                 WfT[o][768+i] = sum_m co_w[i][m]*out_w[768+m][o]
  gemm_t_k<0><<<dim3(6, 6), 256, 0, stream>>>(
      roB, 768, outwT, 1536, zb, 768,
      (const u16*)nullptr, 0, 0, (void*)WfT, 1536,
      nullptr, nullptr, nullptr, nullptr, nullptr, nullptr);
  gemm_t_k<0><<<dim3(6, 6), 256, 0, stream>>>(
      coB, 768, outwT + 768, 1536, zb, 768,
      (const u16*)nullptr, 0, 0, (void*)(WfT + 768), 1536,
      nullptr, nullptr, nullptr, nullptr, nullptr, nullptr);
  bfin_k<<<dim3(768), 64, 0, stream>>>(bproj, outwT, out_b, bfin);

  // merged proj+final: out = AO[4096,1536] @ WfT^T + bfin -> fp32
  gemm_t_k<1><<<dim3(32, 6), 256, 0, stream>>>(
      WfT, 1536, AO, 1536, bfin, 1536,
      (const u16*)nullptr, 0, 0, d_out, 768,
      nullptr, nullptr, nullptr, nullptr, nullptr, nullptr);
}

// Round 8
// 449.131 us; speedup vs baseline: 1.1035x; 1.1035x over previous
//
#include <hip/hip_runtime.h>
#include <hip/hip_bf16.h>

using u16 = unsigned short;
using u32 = unsigned int;
typedef short short8 __attribute__((ext_vector_type(8)));
typedef float f32x4 __attribute__((ext_vector_type(4)));

#define B_  2
#define S_  2048
#define E_  768
#define BS_ 4096

#define L2E_ 1.44269504088896f
#define FML2_ 17.3123404906676f   // 12.0 * log2(e) fixed softmax stabilizer

__device__ __forceinline__ u16 f2bf(float f) {
  __hip_bfloat16 h = __float2bfloat16(f);
  return *reinterpret_cast<u16*>(&h);
}

__device__ __forceinline__ float bf2f(u16 b) {
  u32 bits = (u32)b << 16;
  return *reinterpret_cast<float*>(&bits);
}

__device__ __forceinline__ u32 pk2(float a, float b) {
  return (u32)f2bf(a) | ((u32)f2bf(b) << 16);
}

// async global->LDS, 16B per lane. LDS dest must be wave-uniform base + lane*16.
__device__ __forceinline__ void gld16(const void* g, void* l) {
  __builtin_amdgcn_global_load_lds(
      (const __attribute__((address_space(1))) u32*)g,
      (__attribute__((address_space(3))) u32*)l, 16, 0, 0);
}

// ---------------- conversion / misc kernels ----------------

__global__ __launch_bounds__(256) void conv_x_k(const float* __restrict__ x,
                                                u16* __restrict__ xb, int n4) {
  int i = blockIdx.x * 256 + threadIdx.x;
  if (i >= n4) return;
  float4 v = reinterpret_cast<const float4*>(x)[i];
  reinterpret_cast<uint2*>(xb)[i] = make_uint2(pk2(v.x, v.y), pk2(v.z, v.w));
}

__global__ __launch_bounds__(256) void bias_k(
    const float* rqb, const float* rkb, const float* rvb,
    const float* cqb, const float* ckb, const float* cvb,
    const float* rob, const float* cob,
    const float* rcb, const float* ccb,
    float* bqkv, float* bproj) {
  int t = blockIdx.x * 256 + threadIdx.x;
  if (t < 4608) {
    int seg = t / 768, i = t - seg * 768;
    float v = 0.f;
    if      (seg == 0) v = rqb[i] + rcb[i];   // cultural bias folds into Q bias
    else if (seg == 1) v = rkb[i];
    else if (seg == 2) v = rvb[i];
    else if (seg == 3) v = cqb[i] + ccb[i];
    else if (seg == 4) v = ckb[i];
    else               v = cvb[i];
    bqkv[t] = v;
  } else {
    int u = t - 4608;
    if (u < 1536) bproj[u] = (u < 768) ? rob[u] : cob[u - 768];
  }
}

struct TP {
  const float* src[9];
  u16* dst[9];
  int rows[9];
};

// dst[c][r] = bf16(src[r][c]); src is [rows][768]
__global__ __launch_bounds__(256) void transpose_k(TP p) {
  int mi = blockIdx.z;
  int rows = p.rows[mi];
  int r0 = blockIdx.y * 32;
  if (r0 >= rows) return;
  int c0 = blockIdx.x * 32;
  const float* src = p.src[mi];
  u16* dst = p.dst[mi];
  __shared__ float t[32][33];
  int tx = threadIdx.x & 31, ty = threadIdx.x >> 5;
#pragma unroll
  for (int d = 0; d < 4; ++d) {
    int r = ty + d * 8;
    t[r][tx] = src[(size_t)(r0 + r) * 768 + c0 + tx];
  }
  __syncthreads();
#pragma unroll
  for (int d = 0; d < 4; ++d) {
    int c = ty + d * 8;
    dst[(size_t)(c0 + c) * rows + r0 + tx] = f2bf(t[tx][c]);
  }
}

// ============ transposed GEMM: computes C^T with A[M][K], BT[N][K]; lane's 4
// acc values are CONSECUTIVE M-rows -> packed 8B stores.
// MODE 0: bf16 -> Cout[col*ldc+row] (m-split A select), MODE 1: fp32 float4,
// MODE 2: QKVT routing ====

template<int MODE>
__global__ __launch_bounds__(256) void gemm_t_k(
    const u16* __restrict__ A, int lda,
    const u16* __restrict__ BT, int ldb,
    const float* __restrict__ bias, int K,
    const u16* __restrict__ A2, int msplit, int bofs,
    void* __restrict__ Cout, int ldc,
    u16* __restrict__ Qr, u16* __restrict__ Kr, u16* __restrict__ Vtr,
    u16* __restrict__ Qc, u16* __restrict__ Kc, u16* __restrict__ Vtc) {
  __shared__ u16 lA[128 * 32];
  __shared__ u16 lB[128 * 32];
  const int tid = threadIdx.x, w = tid >> 6, lane = tid & 63;
  const int quad = lane >> 4, l15 = lane & 15;
  const int m0 = blockIdx.y * 128, n0 = blockIdx.x * 128;
  if (msplit && m0 >= msplit) { A = A2 - (size_t)msplit * lda; BT += bofs; }

  const f32x4 z4 = {0.f, 0.f, 0.f, 0.f};
  f32x4 acc[4][4];
#pragma unroll
  for (int i = 0; i < 4; ++i)
#pragma unroll
    for (int j = 0; j < 4; ++j) acc[i][j] = z4;

  const int sr = w * 32 + (lane >> 2);
  const int scp = lane & 3;

  for (int kt = 0; kt < K; kt += 32) {
    int r1 = sr, r2 = sr + 16;
    int c1 = (scp - (r1 >> 2)) & 3;
    int c2 = (scp - (r2 >> 2)) & 3;
    gld16(A + (size_t)(m0 + r1) * lda + kt + c1 * 8, &lA[r1 * 32 + scp * 8]);
    gld16(A + (size_t)(m0 + r2) * lda + kt + c2 * 8, &lA[r2 * 32 + scp * 8]);
    gld16(BT + (size_t)(n0 + r1) * ldb + kt + c1 * 8, &lB[r1 * 32 + scp * 8]);
    gld16(BT + (size_t)(n0 + r2) * ldb + kt + c2 * 8, &lB[r2 * 32 + scp * 8]);
    __syncthreads();
    short8 af[4], bg[4];
#pragma unroll
    for (int i = 0; i < 4; ++i) {
      int r = (w >> 1) * 64 + i * 16 + l15;
      af[i] = *reinterpret_cast<const short8*>(&lA[r * 32 + ((quad + (r >> 2)) & 3) * 8]);
    }
#pragma unroll
    for (int j = 0; j < 4; ++j) {
      int r = (w & 1) * 64 + j * 16 + l15;
      bg[j] = *reinterpret_cast<const short8*>(&lB[r * 32 + ((quad + (r >> 2)) & 3) * 8]);
    }
#pragma unroll
    for (int i = 0; i < 4; ++i)
#pragma unroll
      for (int j = 0; j < 4; ++j)
        acc[i][j] = __builtin_amdgcn_mfma_f32_16x16x32_bf16(af[i], bg[j], acc[i][j], 0, 0, 0);
    __syncthreads();
  }

  const int seg = (MODE == 2) ? (m0 / 768) : 0;
#pragma unroll
  for (int i = 0; i < 4; ++i) {
    int f = m0 + (w >> 1) * 64 + i * 16 + quad * 4;   // M-row base (4 consecutive)
    float4 b4 = *reinterpret_cast<const float4*>(bias + f);
#pragma unroll
    for (int j = 0; j < 4; ++j) {
      int t = n0 + (w & 1) * 64 + j * 16 + l15;        // N-col
      float v0 = acc[i][j][0] + b4.x;
      float v1 = acc[i][j][1] + b4.y;
      float v2 = acc[i][j][2] + b4.z;
      float v3 = acc[i][j][3] + b4.w;
      if (MODE == 0) {
        *reinterpret_cast<uint2*>((u16*)Cout + (size_t)t * ldc + f) =
            make_uint2(pk2(v0, v1), pk2(v2, v3));
      } else if (MODE == 1) {
        *reinterpret_cast<float4*>((float*)Cout + (size_t)t * ldc + f) =
            make_float4(v0, v1, v2, v3);
      } else {
        int b = t >> 11, s = t & 2047;
        int fs = f - seg * 768;
        if (seg == 0) {
          int h = fs >> 7, d = fs & 127;
          *reinterpret_cast<uint2*>(Qr + ((size_t)(b * 6 + h) * 2048 + s) * 128 + d) =
              make_uint2(pk2(v0, v1), pk2(v2, v3));
        } else if (seg == 1) {
          int h = fs >> 7, d = fs & 127;
          *reinterpret_cast<uint2*>(Kr + ((size_t)(b * 6 + h) * 2048 + s) * 128 + d) =
              make_uint2(pk2(v0, v1), pk2(v2, v3));
        } else if (seg == 2) {
          int h = fs >> 7, d = fs & 127;
          u16* vp = Vtr + ((size_t)(b * 6 + h) * 128 + d) * 2048 + s;
          vp[0] = f2bf(v0); vp[2048] = f2bf(v1); vp[4096] = f2bf(v2); vp[6144] = f2bf(v3);
        } else if (seg == 3) {
          int h = fs / 384, d = fs - h * 384;
          *reinterpret_cast<uint2*>(Qc + ((size_t)(b * 2 + h) * 2048 + s) * 384 + d) =
              make_uint2(pk2(v0, v1), pk2(v2, v3));
        } else if (seg == 4) {
          int h = fs / 384, d = fs - h * 384;
          *reinterpret_cast<uint2*>(Kc + ((size_t)(b * 2 + h) * 2048 + s) * 384 + d) =
              make_uint2(pk2(v0, v1), pk2(v2, v3));
        } else {
          int h = fs / 384, d = fs - h * 384;
          u16* vp = Vtc + ((size_t)(b * 2 + h) * 384 + d) * 2048 + s;
          vp[0] = f2bf(v0); vp[2048] = f2bf(v1); vp[4096] = f2bf(v2); vp[6144] = f2bf(v3);
        }
      }
    }
  }
}

// ---------------- fused regular-branch attention, key-split ----------------
// grid (384, 4): blockIdx.x -> (head, 64-query stripe) [XCD-swizzled],
// blockIdx.y = key split (512 keys each). Direct global->VGPR fragment loads
// for Q/K/V; only P goes through LDS (double-buffered -> 1 barrier/tile).
// Writes l-normalized partial O (bf16) + l per row for the combine pass.
__global__ __launch_bounds__(256) void attn_freg_k(
    const u16* __restrict__ Qr, const u16* __restrict__ Kr,
    const u16* __restrict__ Vtr, const float* __restrict__ am,
    u16* __restrict__ OP, float* __restrict__ Lr, float scl) {
  __shared__ u16 lP[2][64 * 128];   // 32 KB double-buffered P tile
  __shared__ float lL[2][64];

  const int tid = threadIdx.x, w = tid >> 6, lane = tid & 63;
  const int quad = lane >> 4, l15 = lane & 15;
  // XCD swizzle: group each head's stripes for K/V L2 reuse
  const int L = blockIdx.x;
  const int gg = (L & 7) * 48 + (L >> 3);   // [0,384)
  const int bh = gg >> 5;                    // head [0,12)
  const int q0 = (gg & 31) * 64;             // query stripe
  const int split = blockIdx.y;              // key split [0,4)
  const int b = bh / 6;
  const int khalf = w >> 1, qhalf = w & 1;

  const u16* Qb = Qr + ((size_t)bh * S_ + q0) * 128;
  const u16* Kb0 = Kr + (size_t)bh * S_ * 128 + (size_t)split * 512 * 128;
  const u16* Vb0 = Vtr + (size_t)bh * 128 * S_ + split * 512;
  const float* amb = am + b * S_ + split * 512;

  // Q fragments (B-operand): n=q=l15, kdim = c*32 + quad*8
  short8 qf[2][4];
#pragma unroll
  for (int j = 0; j < 2; ++j)
#pragma unroll
    for (int c = 0; c < 4; ++c)
      qf[j][c] = *reinterpret_cast<const short8*>(
          Qb + (size_t)(qhalf * 32 + j * 16 + l15) * 128 + c * 32 + quad * 8);

  const f32x4 z4 = {0.f, 0.f, 0.f, 0.f};
  f32x4 accO[4][2];
#pragma unroll
  for (int i = 0; i < 4; ++i)
#pragma unroll
    for (int j = 0; j < 2; ++j) accO[i][j] = z4;
  float lsum[2] = {0.f, 0.f};

  for (int tt = 0; tt < 4; ++tt) {
    u16* lPb = lP[tt & 1];
    // ---- S = K·Q^T : direct K fragment loads ----
    f32x4 accS[4][2];
#pragma unroll
    for (int i = 0; i < 4; ++i)
#pragma unroll
      for (int j = 0; j < 2; ++j) accS[i][j] = z4;
    const u16* Kt = Kb0 + (size_t)tt * 128 * 128;
#pragma unroll
    for (int c = 0; c < 4; ++c) {
      short8 kf[4];
#pragma unroll
      for (int i = 0; i < 4; ++i)
        kf[i] = *reinterpret_cast<const short8*>(
            Kt + (size_t)(khalf * 64 + i * 16 + l15) * 128 + c * 32 + quad * 8);
#pragma unroll
      for (int i = 0; i < 4; ++i)
#pragma unroll
        for (int j = 0; j < 2; ++j)
          accS[i][j] = __builtin_amdgcn_mfma_f32_16x16x32_bf16(kf[i], qf[j][c], accS[i][j], 0, 0, 0);
    }

    // ---- exp + P -> LDS (xor-16 swizzle), dbuf so no pre-write barrier ----
#pragma unroll
    for (int i = 0; i < 4; ++i) {
      int kb = khalf * 64 + i * 16 + quad * 4;
      float4 a4 = *reinterpret_cast<const float4*>(amb + tt * 128 + kb);
      float p0c = fmaf(a4.x, L2E_, -FML2_);
      float p1c = fmaf(a4.y, L2E_, -FML2_);
      float p2c = fmaf(a4.z, L2E_, -FML2_);
      float p3c = fmaf(a4.w, L2E_, -FML2_);
#pragma unroll
      for (int j = 0; j < 2; ++j) {
        int q = qhalf * 32 + j * 16 + l15;
        float p0 = exp2f(fmaf(accS[i][j][0], scl, p0c));
        float p1 = exp2f(fmaf(accS[i][j][1], scl, p1c));
        float p2 = exp2f(fmaf(accS[i][j][2], scl, p2c));
        float p3 = exp2f(fmaf(accS[i][j][3], scl, p3c));
        lsum[j] += (p0 + p1) + (p2 + p3);
        int s = ((kb >> 3) ^ (q & 15));
        *reinterpret_cast<uint2*>(&lPb[q * 128 + s * 8 + (kb & 7)]) =
            make_uint2(pk2(p0, p1), pk2(p2, p3));
      }
    }
    __syncthreads();   // lP visible (single barrier per tile)

    // ---- O += V·P^T : direct V fragment loads ----
#pragma unroll
    for (int c = 0; c < 4; ++c) {
      short8 vf[4];
#pragma unroll
      for (int i = 0; i < 4; ++i)
        vf[i] = *reinterpret_cast<const short8*>(
            Vb0 + (size_t)(khalf * 64 + i * 16 + l15) * S_ + tt * 128 + c * 32 + quad * 8);
      short8 bg[2];
#pragma unroll
      for (int j = 0; j < 2; ++j) {
        int q = qhalf * 32 + j * 16 + l15;
        int s = (4 * c + quad) ^ (q & 15);
        bg[j] = *reinterpret_cast<const short8*>(&lPb[q * 128 + s * 8]);
      }
#pragma unroll
      for (int i = 0; i < 4; ++i)
#pragma unroll
        for (int j = 0; j < 2; ++j)
          accO[i][j] = __builtin_amdgcn_mfma_f32_16x16x32_bf16(vf[i], bg[j], accO[i][j], 0, 0, 0);
    }
  }

  // ---- l reduction across quads and k-half waves ----
#pragma unroll
  for (int j = 0; j < 2; ++j) {
    float s = lsum[j];
    s += __shfl_xor(s, 16);
    s += __shfl_xor(s, 32);
    if (lane < 16) lL[khalf][qhalf * 32 + j * 16 + lane] = s;
  }
  __syncthreads();

  float invl[2];
#pragma unroll
  for (int j = 0; j < 2; ++j) {
    int q = qhalf * 32 + j * 16 + l15;
    invl[j] = 1.f / (lL[0][q] + lL[1][q]);
  }
  const size_t ob = ((size_t)(split * 12 + bh)) * S_ + q0;
#pragma unroll
  for (int i = 0; i < 4; ++i) {
    int d = khalf * 64 + i * 16 + quad * 4;
#pragma unroll
    for (int j = 0; j < 2; ++j) {
      int tl = qhalf * 32 + j * 16 + l15;
      float v0 = accO[i][j][0] * invl[j];
      float v1 = accO[i][j][1] * invl[j];
      float v2 = accO[i][j][2] * invl[j];
      float v3 = accO[i][j][3] * invl[j];
      *reinterpret_cast<uint2*>(OP + (ob + tl) * 128 + d) =
          make_uint2(pk2(v0, v1), pk2(v2, v3));
    }
  }
  if (tid < 64)
    Lr[((size_t)(split * 12 + bh)) * S_ + q0 + tid] = lL[0][tid] + lL[1][tid];
}

// ---------------- regular split combine: AO = sum_s l_s*O_s / sum_s l_s ----
__global__ __launch_bounds__(256) void comb_reg_k(
    const u16* __restrict__ OP, const float* __restrict__ Lr,
    u16* __restrict__ AO) {
  int g = blockIdx.x * 256 + threadIdx.x;   // bh*32768 + q*16 + c
  int c = g & 15;
  int q = (g >> 4) & 2047;
  int bh = g >> 15;                          // [0,12)
  int b = bh / 6, h = bh - b * 6;
  float ls[4], tot = 0.f;
#pragma unroll
  for (int s = 0; s < 4; ++s) {
    ls[s] = Lr[((size_t)(s * 12 + bh)) * S_ + q];
    tot += ls[s];
  }
  float inv = 1.f / tot;
  float acc[8];
#pragma unroll
  for (int e = 0; e < 8; ++e) acc[e] = 0.f;
#pragma unroll
  for (int s = 0; s < 4; ++s) {
    short8 v = *reinterpret_cast<const short8*>(
        OP + (((size_t)(s * 12 + bh)) * S_ + q) * 128 + c * 8);
    float cf = ls[s];
#pragma unroll
    for (int e = 0; e < 8; ++e) acc[e] += cf * bf2f((u16)v[e]);
  }
  u16 o[8];
#pragma unroll
  for (int e = 0; e < 8; ++e) o[e] = f2bf(acc[e] * inv);
  *reinterpret_cast<uint4*>(AO + ((size_t)(b * S_ + q)) * 1536 + h * 128 + c * 8) =
      *reinterpret_cast<uint4*>(o);
}

// ---------------- cultural g1 (transposed): S^T[k][q] = K·Q^T ----------------
__global__ __launch_bounds__(256) void attn_g1_k(
    const u16* __restrict__ Qc, const u16* __restrict__ Kc,
    u16* __restrict__ Pc, float* __restrict__ Lp,
    const float* __restrict__ am, const float* __restrict__ cmask,
    float sCul) {
  __shared__ u16 lA[128 * 32];
  __shared__ u16 lB[128 * 32];
  const int tid = threadIdx.x, w = tid >> 6, lane = tid & 63;
  const int quad = lane >> 4, l15 = lane & 15;
  const int m0 = blockIdx.y * 128, n0 = blockIdx.x * 128;  // m=key, n=query
  const int hc = blockIdx.z;
  const int K = 384;
  const u16* A = Kc + (size_t)hc * S_ * 384;
  const u16* BT = Qc + (size_t)hc * S_ * 384;
  u16* P = Pc + (size_t)hc * (size_t)S_ * S_;
  const int b = hc >> 1;
  const float* cm = cmask + (size_t)b * S_ * S_;
  const float scl = sCul;

  const f32x4 z4 = {0.f, 0.f, 0.f, 0.f};
  f32x4 acc[4][4];
#pragma unroll
  for (int i = 0; i < 4; ++i)
#pragma unroll
    for (int j = 0; j < 4; ++j) acc[i][j] = z4;

  const int sr = w * 32 + (lane >> 2);
  const int scp = lane & 3;

  for (int kt = 0; kt < K; kt += 32) {
    int r1 = sr, r2 = sr + 16;
    int c1 = (scp - (r1 >> 2)) & 3;
    int c2 = (scp - (r2 >> 2)) & 3;
    gld16(A + (size_t)(m0 + r1) * K + kt + c1 * 8, &lA[r1 * 32 + scp * 8]);
    gld16(A + (size_t)(m0 + r2) * K + kt + c2 * 8, &lA[r2 * 32 + scp * 8]);
    gld16(BT + (size_t)(n0 + r1) * K + kt + c1 * 8, &lB[r1 * 32 + scp * 8]);
    gld16(BT + (size_t)(n0 + r2) * K + kt + c2 * 8, &lB[r2 * 32 + scp * 8]);
    __syncthreads();
    short8 af[4], bg[4];
#pragma unroll
    for (int i = 0; i < 4; ++i) {
      int r = (w >> 1) * 64 + i * 16 + l15;
      af[i] = *reinterpret_cast<const short8*>(&lA[r * 32 + ((quad + (r >> 2)) & 3) * 8]);
    }
#pragma unroll
    for (int j = 0; j < 4; ++j) {
      int r = (w & 1) * 64 + j * 16 + l15;
      bg[j] = *reinterpret_cast<const short8*>(&lB[r * 32 + ((quad + (r >> 2)) & 3) * 8]);
    }
#pragma unroll
    for (int i = 0; i < 4; ++i)
#pragma unroll
      for (int j = 0; j < 4; ++j)
        acc[i][j] = __builtin_amdgcn_mfma_f32_16x16x32_bf16(af[i], bg[j], acc[i][j], 0, 0, 0);
    __syncthreads();
  }

  const float* amb = am + b * S_;
  float lsum[4] = {0.f, 0.f, 0.f, 0.f};
#pragma unroll
  for (int i = 0; i < 4; ++i) {
    int kb = m0 + (w >> 1) * 64 + i * 16 + quad * 4;    // 4 consecutive keys
    float4 a4 = *reinterpret_cast<const float4*>(amb + kb);
    float pre0 = fmaf(a4.x, L2E_, -FML2_);
    float pre1 = fmaf(a4.y, L2E_, -FML2_);
    float pre2 = fmaf(a4.z, L2E_, -FML2_);
    float pre3 = fmaf(a4.w, L2E_, -FML2_);
#pragma unroll
    for (int j = 0; j < 4; ++j) {
      int q = n0 + (w & 1) * 64 + j * 16 + l15;
      float4 cmv = *reinterpret_cast<const float4*>(cm + (size_t)q * S_ + kb);
      float c0 = fmaf(cmv.x, L2E_, pre0);
      float c1 = fmaf(cmv.y, L2E_, pre1);
      float c2 = fmaf(cmv.z, L2E_, pre2);
      float c3 = fmaf(cmv.w, L2E_, pre3);
      float p0 = exp2f(fmaf(acc[i][j][0], scl, c0));
      float p1 = exp2f(fmaf(acc[i][j][1], scl, c1));
      float p2 = exp2f(fmaf(acc[i][j][2], scl, c2));
      float p3 = exp2f(fmaf(acc[i][j][3], scl, c3));
      lsum[j] += (p0 + p1) + (p2 + p3);
      *reinterpret_cast<uint2*>(P + (size_t)q * S_ + kb) =
          make_uint2(pk2(p0, p1), pk2(p2, p3));
    }
  }
#pragma unroll
  for (int j = 0; j < 4; ++j) {
    float s = lsum[j];
    s += __shfl_xor(s, 16);
    s += __shfl_xor(s, 32);
    if (lane < 16)
      Lp[(size_t)hc * (32 * S_) + ((size_t)((m0 >> 7) * 2 + (w >> 1))) * S_ +
         n0 + (w & 1) * 64 + j * 16 + lane] = s;
  }
}

// ---------------- cultural g2 (transposed): O^T[d][q] = Vt·P^T ----------------
__global__ __launch_bounds__(256) void attn_g2_k(
    const u16* __restrict__ Pc, const u16* __restrict__ Vtc,
    const float* __restrict__ Lp, u16* __restrict__ AO) {
  const int hc = blockIdx.z;
  const int m0 = blockIdx.y * 128, n0 = blockIdx.x * 128;  // m=feat, n=query
  const u16* A = Vtc + (size_t)hc * 384 * S_;
  const u16* BT = Pc + (size_t)hc * (size_t)S_ * S_;
  const int b = hc >> 1;
  const int colbase = 768 + (hc & 1) * 384;
  __shared__ u16 lA[128 * 32];
  __shared__ u16 lB[128 * 32];
  __shared__ float lL[128];
  const int tid = threadIdx.x, w = tid >> 6, lane = tid & 63;
  const int quad = lane >> 4, l15 = lane & 15;

  if (tid < 128) {
    const float* lp = Lp + (size_t)hc * (32 * S_) + (n0 + tid);
    float s = 0.f;
#pragma unroll
    for (int g = 0; g < 32; ++g) s += lp[(size_t)g * S_];
    lL[tid] = 1.f / s;
  }

  const f32x4 z4 = {0.f, 0.f, 0.f, 0.f};
  f32x4 acc[4][4];
#pragma unroll
  for (int i = 0; i < 4; ++i)
#pragma unroll
    for (int j = 0; j < 4; ++j) acc[i][j] = z4;

  const int sr = w * 32 + (lane >> 2);
  const int scp = lane & 3;

  for (int kt = 0; kt < S_; kt += 32) {
    int r1 = sr, r2 = sr + 16;
    int c1 = (scp - (r1 >> 2)) & 3;
    int c2 = (scp - (r2 >> 2)) & 3;
    gld16(A + (size_t)(m0 + r1) * S_ + kt + c1 * 8, &lA[r1 * 32 + scp * 8]);
    gld16(A + (size_t)(m0 + r2) * S_ + kt + c2 * 8, &lA[r2 * 32 + scp * 8]);
    gld16(BT + (size_t)(n0 + r1) * S_ + kt + c1 * 8, &lB[r1 * 32 + scp * 8]);
    gld16(BT + (size_t)(n0 + r2) * S_ + kt + c2 * 8, &lB[r2 * 32 + scp * 8]);
    __syncthreads();
    short8 af[4], bg[4];
#pragma unroll
    for (int i = 0; i < 4; ++i) {
      int r = (w >> 1) * 64 + i * 16 + l15;
      af[i] = *reinterpret_cast<const short8*>(&lA[r * 32 + ((quad + (r >> 2)) & 3) * 8]);
    }
#pragma unroll
    for (int j = 0; j < 4; ++j) {
      int r = (w & 1) * 64 + j * 16 + l15;
      bg[j] = *reinterpret_cast<const short8*>(&lB[r * 32 + ((quad + (r >> 2)) & 3) * 8]);
    }
#pragma unroll
    for (int i = 0; i < 4; ++i)
#pragma unroll
      for (int j = 0; j < 4; ++j)
        acc[i][j] = __builtin_amdgcn_mfma_f32_16x16x32_bf16(af[i], bg[j], acc[i][j], 0, 0, 0);
    __syncthreads();
  }

  float invl[4];
#pragma unroll
  for (int j = 0; j < 4; ++j) invl[j] = lL[(w & 1) * 64 + j * 16 + l15];
#pragma unroll
  for (int i = 0; i < 4; ++i) {
    int feat = colbase + m0 + (w >> 1) * 64 + i * 16 + quad * 4;
#pragma unroll
    for (int j = 0; j < 4; ++j) {
      int q = n0 + (w & 1) * 64 + j * 16 + l15;
      float v0 = acc[i][j][0] * invl[j];
      float v1 = acc[i][j][1] * invl[j];
      float v2 = acc[i][j][2] * invl[j];
      float v3 = acc[i][j][3] * invl[j];
      *reinterpret_cast<uint2*>(AO + ((size_t)(b * S_ + q)) * 1536 + feat) =
          make_uint2(pk2(v0, v1), pk2(v2, v3));
    }
  }
}

// ---------------- launcher ----------------

extern "C" void kernel_launch(void* const* d_in, const int* in_sizes, int n_in,
                              void* d_out, int out_size, void* d_ws, size_t ws_size,
                              hipStream_t stream) {
  const float* x     = (const float*)d_in[0];
  const float* cmask = (const float*)d_in[1];
  const float* amask = (const float*)d_in[2];
  const float* W[8]  = { (const float*)d_in[3], (const float*)d_in[4], (const float*)d_in[5],
                         (const float*)d_in[6], (const float*)d_in[7], (const float*)d_in[8],
                         (const float*)d_in[9], (const float*)d_in[10] };
  const float* rq_b = (const float*)d_in[11];
  const float* rk_b = (const float*)d_in[12];
  const float* rv_b = (const float*)d_in[13];
  const float* ro_b = (const float*)d_in[14];
  const float* cq_b = (const float*)d_in[15];
  const float* ck_b = (const float*)d_in[16];
  const float* cv_b = (const float*)d_in[17];
  const float* co_b = (const float*)d_in[18];
  const float* r_cb = (const float*)d_in[19];
  const float* c_cb = (const float*)d_in[20];
  const float* out_w = (const float*)d_in[21];
  const float* out_b = (const float*)d_in[22];

  char* p = (char*)d_ws;
  auto carve = [&](size_t bytes) -> void* {
    void* r = (void*)p;
    p += (bytes + 255) & ~(size_t)255;
    return r;
  };
  u16* Xb    = (u16*)carve((size_t)BS_ * E_ * 2);       // dead after QKV gemm
  u16* WqkvT = (u16*)carve((size_t)4608 * 768 * 2);     // dead after QKV gemm
  u16* roT   = (u16*)carve((size_t)768 * 768 * 2);
  u16* coT   = (u16*)carve((size_t)768 * 768 * 2);
  u16* outwT = (u16*)carve((size_t)768 * 1536 * 2);
  float* bqkv  = (float*)carve(4608 * 4);
  float* bproj = (float*)carve(1536 * 4);
  u16* Qr  = (u16*)carve((size_t)B_ * 6 * S_ * 128 * 2);
  u16* Kr  = (u16*)carve((size_t)B_ * 6 * S_ * 128 * 2);
  u16* Vtr = (u16*)carve((size_t)B_ * 6 * S_ * 128 * 2);
  u16* Qc  = (u16*)carve((size_t)B_ * 2 * S_ * 384 * 2);
  u16* Kc  = (u16*)carve((size_t)B_ * 2 * S_ * 384 * 2);
  u16* Vtc = (u16*)carve((size_t)B_ * 2 * S_ * 384 * 2);
  u16* AO  = (u16*)carve((size_t)BS_ * 1536 * 2);
  u16* Pcul = (u16*)carve((size_t)4 * S_ * S_ * 2);     // 33.6 MB
  u16* OPr  = (u16*)carve((size_t)4 * 12 * S_ * 128 * 2);  // 25.2 MB reg partials
  float* Lrg = (float*)carve((size_t)4 * 12 * S_ * 4);
  // Lp (cultural l partials) aliases dead Xb region (1 MB <= 6.3 MB)
  float* Lp = (float*)Xb;
  u16* PR = Pcul;  // proj output: Pcul dead after attn_g2

  const float sReg = 0.08838834764831845f * L2E_;
  const float sCul = 0.05103103630798288f * L2E_;

  conv_x_k<<<dim3(BS_ * E_ / 4 / 256), 256, 0, stream>>>(x, Xb, BS_ * E_ / 4);
  bias_k<<<dim3(24), 256, 0, stream>>>(rq_b, rk_b, rv_b, cq_b, ck_b, cv_b,
                                       ro_b, co_b, r_cb, c_cb, bqkv, bproj);

  TP tp;
  const int wsel[6] = {0, 1, 2, 4, 5, 6};  // rq rk rv cq ck cv
  for (int i = 0; i < 6; ++i) {
    tp.src[i] = W[wsel[i]];
    tp.dst[i] = WqkvT + (size_t)i * 768 * 768;
    tp.rows[i] = 768;
  }
  tp.src[6] = W[3]; tp.dst[6] = roT;   tp.rows[6] = 768;   // ro_w
  tp.src[7] = W[7]; tp.dst[7] = coT;   tp.rows[7] = 768;   // co_w
  tp.src[8] = out_w; tp.dst[8] = outwT; tp.rows[8] = 1536; // out_w
  transpose_k<<<dim3(24, 48, 9), 256, 0, stream>>>(tp);

  // fused QKV projection, transposed: M=4608 features, N=4096 tokens
  gemm_t_k<2><<<dim3(32, 36), 256, 0, stream>>>(
      WqkvT, 768, Xb, 768, bqkv, 768,
      (const u16*)nullptr, 0, 0, (void*)nullptr, 0,
      Qr, Kr, Vtr, Qc, Kc, Vtc);

  // regular branch: fused attention, key-split x4 (1536 blocks)
  attn_freg_k<<<dim3(384, 4), 256, 0, stream>>>(Qr, Kr, Vtr, amask, OPr, Lrg, sReg);

  // cultural branch: two-GEMM path
  attn_g1_k<<<dim3(16, 16, 4), 256, 0, stream>>>(
      Qc, Kc, Pcul, Lp, amask, cmask, sCul);
  attn_g2_k<<<dim3(16, 3, 4), 256, 0, stream>>>(Pcul, Vtc, Lp, AO);

  // combine regular partials into AO
  comb_reg_k<<<dim3(12 * S_ * 16 / 256), 256, 0, stream>>>(OPr, Lrg, AO);

  // merged per-branch output projections, transposed (m-split selects coT)
  gemm_t_k<0><<<dim3(32, 12), 256, 0, stream>>>(
      roT, 768, AO, 1536, bproj, 768,
      coT, 768, 768, (void*)PR, 1536,
      nullptr, nullptr, nullptr, nullptr, nullptr, nullptr);

  // final, transposed: M=768 out-features, N=4096 tokens -> fp32 float4 stores
  gemm_t_k<1><<<dim3(32, 6), 256, 0, stream>>>(
      outwT, 1536, PR, 1536, out_b, 1536,
      (const u16*)nullptr, 0, 0, d_out, 768,
      nullptr, nullptr, nullptr, nullptr, nullptr, nullptr);
}